// Round 14
// baseline (206.232 us; speedup 1.0000x reference)
//
#include <hip/hip_runtime.h>

typedef int v4i __attribute__((ext_vector_type(4)));
typedef unsigned int u32;
typedef __attribute__((address_space(1))) const u32 gas_u32;
typedef __attribute__((address_space(3))) u32 las_u32;

#define THREADS 1024
#define NWAVES 16
#define EPT 8                            // edges per thread per chunk
#define CHUNK (THREADS * EPT)            // 8192
#define NBLK 256                         // persistent: 1 block per CU
#define PART_BITS 18
#define PART_NODES (1 << PART_BITS)      // 262144 nodes per partition
#define PART_WORDS (PART_NODES / 16)     // 16384 words = 64 KB
#define NPART 4
#define TBL 450                          // NUM_RELS * 9
#define FILL_WAVE_WORDS (PART_WORDS / NWAVES)  // 1024 words per wave
#define FILL_PER_WAVE (FILL_WAVE_WORDS / 256)  // 4 DMA instrs per wave
#define PAD_WIDX ((u32)(2 * PART_WORDS))       // zeroed pad word index

// Barrier WITHOUT vmcnt drain (DMA/stream loads stay in flight); rule-18 fence.
#define BAR() do {                                            \
    asm volatile("s_waitcnt lgkmcnt(0)" ::: "memory");        \
    __builtin_amdgcn_s_barrier();                             \
    __builtin_amdgcn_sched_barrier(0);                        \
} while (0)

// Counted vmcnt wait (T4): keep the N newest loads in flight.
#define WAITVM(n) do {                                        \
    asm volatile("s_waitcnt vmcnt(" #n ")" ::: "memory");     \
    __builtin_amdgcn_sched_barrier(0);                        \
} while (0)

#define SBAR() __builtin_amdgcn_sched_barrier(0)

__global__ void zero_kernel(float* __restrict__ out, int n) {
    int i = blockIdx.x * blockDim.x + threadIdx.x;
    if (i < n) out[i] = 0.0f;
}

// Pack node_type (0..2) into 2 bits/node: 16 nodes per uint32 (256 KB total).
__global__ void pack_nt_kernel(const int* __restrict__ nt,
                               unsigned int* __restrict__ packed,
                               int nwords, int N) {
    int i = blockIdx.x * blockDim.x + threadIdx.x;
    if (i >= nwords) return;
    unsigned int word = 0;
    int base = i * 16;
    if (base + 16 <= N) {
        #pragma unroll
        for (int j = 0; j < 4; ++j) {
            int4 v = *reinterpret_cast<const int4*>(nt + base + j * 4);
            word |= (unsigned)(v.x & 3) << (2 * (j * 4 + 0));
            word |= (unsigned)(v.y & 3) << (2 * (j * 4 + 1));
            word |= (unsigned)(v.z & 3) << (2 * (j * 4 + 2));
            word |= (unsigned)(v.w & 3) << (2 * (j * 4 + 3));
        }
    } else {
        for (int j = 0; base + j < N; ++j)
            word |= (unsigned)(nt[base + j] & 3) << (2 * j);
    }
    packed[i] = word;
}

// DMA one 64 KB partition p into LDS half (p&1). Wave-uniform LDS base +
// lane x 16B (m104 pattern); per-lane global source. Zero VGPR cost; 4
// instrs/wave -> the per-wave vmcnt ledger in the main loop.
__device__ __forceinline__ void dma_fill(const u32* __restrict__ pnt,
                                         u32* lds0, int p, int wv, int lane) {
    const u32* g = pnt + (size_t)p * PART_WORDS + wv * FILL_WAVE_WORDS + lane * 4;
    u32* l = lds0 + (p & 1) * PART_WORDS + wv * FILL_WAVE_WORDS;
    #pragma unroll
    for (int i = 0; i < FILL_PER_WAVE; ++i)
        __builtin_amdgcn_global_load_lds((gas_u32*)(g + i * 256),
                                         (las_u32*)(l + i * 256), 16, 0, 0);
}

// Gather pass for compile-time partition P, reading buffer half (P&1).
// ax = part(2b)<<19 | widx(14b)<<5 | shift(5b) -- one packed reg/endpoint
// (R13-proven form; no CSE fodder). Out-of-partition lanes read the zeroed
// pad word (uniform addr = broadcast); contribution auto-vanishes.
template <int P>
__device__ __forceinline__ void gather_phase(const u32* lds_all,
                                             const u32 (&axs)[EPT], const u32 (&axd)[EPT],
                                             int (&enc)[EPT]) {
    #pragma unroll
    for (int k = 0; k < EPT; ++k) {
        u32 as = axs[k];
        u32 idx_s = ((as >> 19) == (u32)P)
                        ? (((as >> 5) & 0x3FFFu) | ((u32)(P & 1) << 14)) : PAD_WIDX;
        u32 ws = lds_all[idx_s];
        u32 ad = axd[k];
        u32 idx_d = ((ad >> 19) == (u32)P)
                        ? (((ad >> 5) & 0x3FFFu) | ((u32)(P & 1) << 14)) : PAD_WIDX;
        u32 wd = lds_all[idx_d];
        int ts = (int)((ws >> (as & 31u)) & 3u);
        int td = (int)((wd >> (ad & 31u)) & 3u);
        enc[k] += ts * 3 + td;
    }
}

// R8 chassis + double-buffered 2x64KB fills: every fill covered by a full
// gather phase. 1024 threads (64-VGPR law) with ~24 persistent live regs.
__launch_bounds__(THREADS)
__global__ void edge_score_k(const u32* __restrict__ pnt,
                             const int* __restrict__ et_g,
                             const int* __restrict__ es_g,
                             const int* __restrict__ ed_g,
                             const int* __restrict__ eb_g,
                             const float* __restrict__ wt,
                             float* __restrict__ out,
                             int nchunk) {
    // [0,16384): half A | [16384,32768): half B | [32768,32784): zero pad |
    // then the 450-entry weight table.
    __shared__ __align__(16) u32 lds_all[2 * PART_WORDS + 16 + TBL];
    float* lw = reinterpret_cast<float*>(lds_all + 2 * PART_WORDS + 16);

    const int tid  = threadIdx.x;
    const int lane = tid & 63;
    const int wv   = tid >> 6;

    if (tid < 16) lds_all[2 * PART_WORDS + tid] = 0u;   // zero pad words
    // lw fill first: its global load is oldest in the vmcnt FIFO, retires
    // before any counted wait matters.
    for (int i = tid; i < TBL; i += THREADS) lw[i] = wt[i];

    const long blk0 = (long)blockIdx.x * ((long)nchunk * CHUNK);
    const long lb   = (long)wv * (64 * EPT) + (long)lane * 4;   // wave window 512

    // prologue: streams for chunk 0 (6 loads), then fill p0 -> A (4 DMA)
    v4i etv[2], svv[2], dvv[2];
    #pragma unroll
    for (int j = 0; j < 2; ++j) {
        etv[j] = __builtin_nontemporal_load((const v4i*)(et_g + blk0 + lb + j * 256));
        svv[j] = __builtin_nontemporal_load((const v4i*)(es_g + blk0 + lb + j * 256));
        dvv[j] = __builtin_nontemporal_load((const v4i*)(ed_g + blk0 + lb + j * 256));
    }
    SBAR();
    dma_fill(pnt, lds_all, 0, wv, lane);
    SBAR();

    for (int c = 0; c < nchunk; ++c) {
        const long cb = blk0 + (long)c * CHUNK + lb;

        // ---- phase 0: gather<0> from A; fill p1 -> B --------------------
        BAR();                                 // prev epilogue done (B free); c0: lds init visible
        dma_fill(pnt, lds_all, 1, wv, lane);   // F1:4
        SBAR();
        v4i eb0 = __builtin_nontemporal_load((const v4i*)(eb_g + cb));
        v4i eb1 = __builtin_nontemporal_load((const v4i*)(eb_g + cb + 256));
        SBAR();
        // FIFO now: [S:6][F0:4][F1:4][eb:2] (compiler auto-waits S before use)
        int enc[EPT]; u32 axs[EPT], axd[EPT];
        #pragma unroll
        for (int j = 0; j < 2; ++j) {
            #pragma unroll
            for (int q = 0; q < 4; ++q) {
                int k = j * 4 + q;
                enc[k] = etv[j][q] * 9;
                u32 s = (u32)svv[j][q];
                u32 d = (u32)dvv[j][q];
                axs[k] = ((s >> PART_BITS) << 19) | (((s >> 4) & 0x3FFFu) << 5) | ((s & 15u) << 1);
                axd[k] = ((d >> PART_BITS) << 19) | (((d >> 4) & 0x3FFFu) << 5) | ((d & 15u) << 1);
            }
        }
        WAITVM(6);                             // F0 landed; F1+eb in flight
        BAR();                                 // p0 resident blockwide
        gather_phase<0>(lds_all, axs, axd, enc);

        // ---- phase 1: gather<1> from B; fill p2 -> A --------------------
        BAR();                                 // gather<0> done (A free)
        dma_fill(pnt, lds_all, 2, wv, lane);   // F2:4   FIFO: [F1:4][eb:2][F2:4]
        SBAR();
        WAITVM(6);                             // F1 landed; eb+F2 in flight
        BAR();
        gather_phase<1>(lds_all, axs, axd, enc);

        // ---- phase 2: gather<2> from A; fill p3 -> B --------------------
        BAR();                                 // gather<1> done (B free)
        dma_fill(pnt, lds_all, 3, wv, lane);   // F3:4   FIFO: [eb:2][F2:4][F3:4]
        SBAR();
        WAITVM(4);                             // F2 (and eb) landed; F3 in flight
        BAR();
        gather_phase<2>(lds_all, axs, axd, enc);

        // ---- phase 3: gather<3> from B; streams' + fill p0' -> A --------
        BAR();                                 // gather<2> done (A free)
        {   // next-chunk streams (clamped on last chunk: keeps vmcnt uniform)
            long nb = (c + 1 < nchunk) ? (cb + CHUNK) : cb;
            #pragma unroll
            for (int j = 0; j < 2; ++j) {
                etv[j] = __builtin_nontemporal_load((const v4i*)(et_g + nb + j * 256));
                svv[j] = __builtin_nontemporal_load((const v4i*)(es_g + nb + j * 256));
                dvv[j] = __builtin_nontemporal_load((const v4i*)(ed_g + nb + j * 256));
            }
        }
        SBAR();
        dma_fill(pnt, lds_all, 0, wv, lane);   // F0':4  FIFO: [F3:4][S':6][F0':4]
        SBAR();
        WAITVM(10);                            // F3 landed; S'+F0' in flight
        BAR();
        gather_phase<3>(lds_all, axs, axd, enc);

        // ---- epilogue: lw lookup + per-graph sum, 1 atomic/wave ---------
        // (eb drained at phase 2's WAITVM(4); S'+F0' stay in flight)
        int wb0 = __shfl(eb0[0], 0);           // first edge of wave window
        int wbL = __shfl(eb1[3], 63);          // last edge of wave window
        if (wb0 == wbL) {                      // sorted => whole window one graph
            float ssum = 0.0f;
            #pragma unroll
            for (int k = 0; k < EPT; ++k) ssum += lw[enc[k]];
            #pragma unroll
            for (int off = 32; off >= 1; off >>= 1)
                ssum += __shfl_down(ssum, off);
            if (lane == 0) atomicAdd(&out[wb0], ssum);
        } else {
            float acc = 0.0f; int cur = -1;
            #pragma unroll
            for (int k = 0; k < EPT; ++k) {
                int bb = (k < 4) ? eb0[k] : eb1[k - 4];   // static index
                if (bb != cur) {
                    if (cur >= 0) atomicAdd(&out[cur], acc);
                    cur = bb; acc = 0.0f;
                }
                acc += lw[enc[k]];
            }
            if (cur >= 0) atomicAdd(&out[cur], acc);
        }
    }
    WAITVM(0);   // drain the tail fill/streams before endpgm
}

// Per-edge fallback / tail kernel (direct gathers; correctness path).
__global__ void edge_score_simple(const int* __restrict__ nt,
                                  const int* __restrict__ et,
                                  const int* __restrict__ es,
                                  const int* __restrict__ ed,
                                  const int* __restrict__ eb,
                                  const float* __restrict__ w,
                                  float* __restrict__ out,
                                  long e0, long E) {
    long e = e0 + (long)blockIdx.x * blockDim.x + threadIdx.x;
    if (e >= E) return;
    int enc = et[e] * 9 + nt[es[e]] * 3 + nt[ed[e]];
    atomicAdd(&out[eb[e]], w[enc]);
}

extern "C" void kernel_launch(void* const* d_in, const int* in_sizes, int n_in,
                              void* d_out, int out_size, void* d_ws, size_t ws_size,
                              hipStream_t stream) {
    const int*   node_type  = (const int*)d_in[0];
    const int*   edge_type  = (const int*)d_in[1];
    const int*   edge_index = (const int*)d_in[2];   // [2, E]: src then dst
    const int*   edge_batch = (const int*)d_in[3];
    const float* w          = (const float*)d_in[4];
    float* out = (float*)d_out;

    long N = in_sizes[0];
    long E = in_sizes[1];
    const int* esrc = edge_index;
    const int* edst = edge_index + E;

    // d_out is poisoned once and never re-poisoned between replays; we
    // accumulate with atomics, so zero it at the start of every launch.
    zero_kernel<<<(out_size + 255) / 256, 256, 0, stream>>>(out, out_size);

    int  nwords = (int)((N + 15) / 16);
    long nchunk = E / ((long)NBLK * CHUNK);            // 8 for E = 2^24
    bool fast_ok = (ws_size >= (size_t)nwords * 4) &&
                   (N <= (long)NPART * PART_NODES) && (nchunk > 0);

    if (fast_ok) {
        unsigned int* pnt = (unsigned int*)d_ws;
        pack_nt_kernel<<<(nwords + 255) / 256, 256, 0, stream>>>(node_type, pnt, nwords, (int)N);

        edge_score_k<<<NBLK, THREADS, 0, stream>>>(
            pnt, edge_type, esrc, edst, edge_batch, w, out, (int)nchunk);

        long covered = (long)NBLK * nchunk * CHUNK;
        long rem     = E - covered;                    // 0 for this dataset
        if (rem > 0) {
            int tb = (int)((rem + 255) / 256);
            edge_score_simple<<<tb, 256, 0, stream>>>(
                node_type, edge_type, esrc, edst, edge_batch, w, out, covered, E);
        }
    } else {
        int tb = (int)((E + 255) / 256);
        edge_score_simple<<<tb, 256, 0, stream>>>(
            node_type, edge_type, esrc, edst, edge_batch, w, out, 0, E);
    }
}

// Round 15
// 182.257 us; speedup vs baseline: 1.1315x; 1.1315x over previous
//
#include <hip/hip_runtime.h>

typedef int v4i __attribute__((ext_vector_type(4)));
typedef unsigned int u32;
typedef __attribute__((address_space(1))) const u32 gas_u32;
typedef __attribute__((address_space(3))) u32 las_u32;

#define THREADS 512
#define NWAVES 8
#define EPT 16                           // edges per thread per chunk
#define CHUNK (THREADS * EPT)            // 8192
#define NBLK 256                         // persistent: 1 block per CU
#define PART_BITS 18
#define PART_NODES (1 << PART_BITS)      // 262144 nodes per partition
#define PART_WORDS (PART_NODES / 16)     // 16384 words = 64 KB
#define NPART 4
#define TBL 450                          // NUM_RELS * 9
#define FILL_WAVE_WORDS (PART_WORDS / NWAVES)  // 2048 words per wave
#define FILL_PER_WAVE (FILL_WAVE_WORDS / 256)  // 8 DMA instrs per wave
#define PAD_WIDX ((u32)(2 * PART_WORDS))       // zeroed pad word index

// Barrier WITHOUT vmcnt drain (DMA/stream loads stay in flight); rule-18 fence.
#define BAR() do {                                            \
    asm volatile("s_waitcnt lgkmcnt(0)" ::: "memory");        \
    __builtin_amdgcn_s_barrier();                             \
    __builtin_amdgcn_sched_barrier(0);                        \
} while (0)

// Counted vmcnt wait (T4): keep the N newest loads in flight.
#define WAITVM(n) do {                                        \
    asm volatile("s_waitcnt vmcnt(" #n ")" ::: "memory");     \
    __builtin_amdgcn_sched_barrier(0);                        \
} while (0)

#define SBAR() __builtin_amdgcn_sched_barrier(0)

__global__ void zero_kernel(float* __restrict__ out, int n) {
    int i = blockIdx.x * blockDim.x + threadIdx.x;
    if (i < n) out[i] = 0.0f;
}

// Pack node_type (0..2) into 2 bits/node: 16 nodes per uint32 (256 KB total).
__global__ void pack_nt_kernel(const int* __restrict__ nt,
                               unsigned int* __restrict__ packed,
                               int nwords, int N) {
    int i = blockIdx.x * blockDim.x + threadIdx.x;
    if (i >= nwords) return;
    unsigned int word = 0;
    int base = i * 16;
    if (base + 16 <= N) {
        #pragma unroll
        for (int j = 0; j < 4; ++j) {
            int4 v = *reinterpret_cast<const int4*>(nt + base + j * 4);
            word |= (unsigned)(v.x & 3) << (2 * (j * 4 + 0));
            word |= (unsigned)(v.y & 3) << (2 * (j * 4 + 1));
            word |= (unsigned)(v.z & 3) << (2 * (j * 4 + 2));
            word |= (unsigned)(v.w & 3) << (2 * (j * 4 + 3));
        }
    } else {
        for (int j = 0; base + j < N; ++j)
            word |= (unsigned)(nt[base + j] & 3) << (2 * j);
    }
    packed[i] = word;
}

// DMA one 64 KB partition p into LDS half (p&1). Wave-uniform LDS base +
// lane x 16B (m104 pattern); per-lane global source. Zero VGPR cost; 8
// instrs/wave -> the per-wave vmcnt ledger in the main loop.
__device__ __forceinline__ void dma_fill(const u32* __restrict__ pnt,
                                         u32* lds0, int p, int wv, int lane) {
    const u32* g = pnt + (size_t)p * PART_WORDS + wv * FILL_WAVE_WORDS + lane * 4;
    u32* l = lds0 + (p & 1) * PART_WORDS + wv * FILL_WAVE_WORDS;
    #pragma unroll
    for (int i = 0; i < FILL_PER_WAVE; ++i)
        __builtin_amdgcn_global_load_lds((gas_u32*)(g + i * 256),
                                         (las_u32*)(l + i * 256), 16, 0, 0);
}

// Gather pass for compile-time partition P, reading buffer half (P&1).
// Out-of-partition lanes read the zeroed pad word (uniform addr = broadcast);
// contribution auto-vanishes -> unconditional accumulate into packed enc
// (two 16-bit fields per reg; max value 457 < 65536, no carry crossover).
template <int P>
__device__ __forceinline__ void gather_phase(const u32* lds_all,
                                             const v4i (&svv)[4], const v4i (&dvv)[4],
                                             u32 (&encp)[8]) {
    #pragma unroll
    for (int k = 0; k < EPT; ++k) {
        u32 s = (u32)svv[k / 4][k % 4];
        u32 idx_s = ((s >> PART_BITS) == (u32)P)
                        ? (((s & (u32)(PART_NODES - 1)) >> 4) | ((u32)(P & 1) << 14))
                        : PAD_WIDX;
        u32 ws = lds_all[idx_s];
        u32 d = (u32)dvv[k / 4][k % 4];
        u32 idx_d = ((d >> PART_BITS) == (u32)P)
                        ? (((d & (u32)(PART_NODES - 1)) >> 4) | ((u32)(P & 1) << 14))
                        : PAD_WIDX;
        u32 wd = lds_all[idx_d];
        u32 ts = (ws >> ((s & 15u) << 1)) & 3u;
        u32 td = (wd >> ((d & 15u) << 1)) & 3u;
        encp[k / 2] += (ts * 3u + td) << ((k & 1) * 16);
    }
}

// 512 threads -> 128-VGPR budget (R13-proven clean regime). Double-buffered
// 2x64KB fills: every fill covered by a full gather phase. Peak live state
// ~80-110 regs by design (packed enc, late eb, post-gather stream prefetch).
__launch_bounds__(THREADS)
__global__ void edge_score_k(const u32* __restrict__ pnt,
                             const int* __restrict__ et_g,
                             const int* __restrict__ es_g,
                             const int* __restrict__ ed_g,
                             const int* __restrict__ eb_g,
                             const float* __restrict__ wt,
                             float* __restrict__ out,
                             int nchunk) {
    // [0,16384): half A | [16384,32768): half B | [32768,32784): zero pad |
    // then the 450-entry weight table.
    __shared__ __align__(16) u32 lds_all[2 * PART_WORDS + 16 + TBL];
    float* lw = reinterpret_cast<float*>(lds_all + 2 * PART_WORDS + 16);

    const int tid  = threadIdx.x;
    const int lane = tid & 63;
    const int wv   = tid >> 6;

    if (tid < 16) lds_all[2 * PART_WORDS + tid] = 0u;   // zero pad words
    for (int i = tid; i < TBL; i += THREADS) lw[i] = wt[i];

    const long blk0 = (long)blockIdx.x * ((long)nchunk * CHUNK);
    const long lb   = (long)wv * (64 * EPT) + (long)lane * 4;   // wave window 1024

    // prologue: streams for chunk 0 (12 loads) then fill p0 -> A (8 DMA)
    v4i etv[4], svv[4], dvv[4];
    #pragma unroll
    for (int j = 0; j < 4; ++j) {
        etv[j] = __builtin_nontemporal_load((const v4i*)(et_g + blk0 + lb + j * 256));
        svv[j] = __builtin_nontemporal_load((const v4i*)(es_g + blk0 + lb + j * 256));
        dvv[j] = __builtin_nontemporal_load((const v4i*)(ed_g + blk0 + lb + j * 256));
    }
    SBAR();
    dma_fill(pnt, lds_all, 0, wv, lane);        // F0 -> A
    SBAR();

    for (int c = 0; c < nchunk; ++c) {
        const long cb = blk0 + (long)c * CHUNK + lb;

        // ---- phase 0: fill p1 -> B; gather<0> from A --------------------
        BAR();                                  // prev epilogue done (B free); c0: lds init visible
        dma_fill(pnt, lds_all, 1, wv, lane);    // F1:8   FIFO [S:12][F0:8][F1:8]
        SBAR();
        u32 encp[8];
        #pragma unroll
        for (int i = 0; i < 8; ++i) {           // auto-wait retires S here
            u32 e0 = (u32)etv[(2 * i) / 4][(2 * i) % 4] * 9u;
            u32 e1 = (u32)etv[(2 * i + 1) / 4][(2 * i + 1) % 4] * 9u;
            encp[i] = e0 | (e1 << 16);
        }
        WAITVM(8);                              // F0 landed; F1 in flight
        BAR();                                  // p0 resident blockwide
        gather_phase<0>(lds_all, svv, dvv, encp);

        // ---- phase 1: fill p2 -> A; gather<1> from B --------------------
        BAR();                                  // gather<0> done (A free)
        dma_fill(pnt, lds_all, 2, wv, lane);    // F2:8   FIFO [F1:8][F2:8]
        SBAR();
        WAITVM(8);                              // F1 landed; F2 in flight
        BAR();
        gather_phase<1>(lds_all, svv, dvv, encp);

        // ---- phase 2: fill p3 -> B; eb loads; gather<2> from A ----------
        BAR();                                  // gather<1> done (B free)
        dma_fill(pnt, lds_all, 3, wv, lane);    // F3:8
        SBAR();
        v4i ebv[4];
        #pragma unroll
        for (int j = 0; j < 4; ++j)
            ebv[j] = __builtin_nontemporal_load((const v4i*)(eb_g + cb + j * 256));
        SBAR();                                 // FIFO [F2:8][F3:8][eb:4]
        WAITVM(12);                             // F2 landed; F3+eb in flight
        BAR();
        gather_phase<2>(lds_all, svv, dvv, encp);

        // ---- phase 3: fill p0' -> A; gather<3> from B -------------------
        BAR();                                  // gather<2> done (A free)
        dma_fill(pnt, lds_all, 0, wv, lane);    // F0':8  FIFO [F3:8][eb:4][F0':8]
        SBAR();
        WAITVM(12);                             // F3 landed; eb+F0' in flight
        BAR();
        gather_phase<3>(lds_all, svv, dvv, encp);

        // ---- next-chunk streams into now-dead stream regs ---------------
        {
            long nb = (c + 1 < nchunk) ? (cb + CHUNK) : cb;   // uniform counts
            #pragma unroll
            for (int j = 0; j < 4; ++j) {
                etv[j] = __builtin_nontemporal_load((const v4i*)(et_g + nb + j * 256));
                svv[j] = __builtin_nontemporal_load((const v4i*)(es_g + nb + j * 256));
                dvv[j] = __builtin_nontemporal_load((const v4i*)(ed_g + nb + j * 256));
            }
        }
        SBAR();                                 // FIFO [eb:4][F0':8][S':12]
        WAITVM(20);                             // eb landed; F0'+S' in flight

        // ---- epilogue: lw lookup + per-graph sum, 1 atomic/wave ---------
        int wb0 = __shfl(ebv[0][0], 0);         // first edge of wave window
        int wbL = __shfl(ebv[3][3], 63);        // last edge of wave window
        if (wb0 == wbL) {                       // sorted => whole window one graph
            float ssum = 0.0f;
            #pragma unroll
            for (int k = 0; k < EPT; ++k) {
                u32 e = (encp[k / 2] >> ((k & 1) * 16)) & 0xFFFFu;
                ssum += lw[e];
            }
            #pragma unroll
            for (int off = 32; off >= 1; off >>= 1)
                ssum += __shfl_down(ssum, off);
            if (lane == 0) atomicAdd(&out[wb0], ssum);
        } else {
            float acc = 0.0f; int cur = -1;
            #pragma unroll
            for (int k = 0; k < EPT; ++k) {
                int bb = ebv[k / 4][k % 4];     // static index
                u32 e = (encp[k / 2] >> ((k & 1) * 16)) & 0xFFFFu;
                if (bb != cur) {
                    if (cur >= 0) atomicAdd(&out[cur], acc);
                    cur = bb; acc = 0.0f;
                }
                acc += lw[e];
            }
            if (cur >= 0) atomicAdd(&out[cur], acc);
        }
    }
    WAITVM(0);   // drain tail fill/streams before endpgm
}

// Per-edge fallback / tail kernel (direct gathers; correctness path).
__global__ void edge_score_simple(const int* __restrict__ nt,
                                  const int* __restrict__ et,
                                  const int* __restrict__ es,
                                  const int* __restrict__ ed,
                                  const int* __restrict__ eb,
                                  const float* __restrict__ w,
                                  float* __restrict__ out,
                                  long e0, long E) {
    long e = e0 + (long)blockIdx.x * blockDim.x + threadIdx.x;
    if (e >= E) return;
    int enc = et[e] * 9 + nt[es[e]] * 3 + nt[ed[e]];
    atomicAdd(&out[eb[e]], w[enc]);
}

extern "C" void kernel_launch(void* const* d_in, const int* in_sizes, int n_in,
                              void* d_out, int out_size, void* d_ws, size_t ws_size,
                              hipStream_t stream) {
    const int*   node_type  = (const int*)d_in[0];
    const int*   edge_type  = (const int*)d_in[1];
    const int*   edge_index = (const int*)d_in[2];   // [2, E]: src then dst
    const int*   edge_batch = (const int*)d_in[3];
    const float* w          = (const float*)d_in[4];
    float* out = (float*)d_out;

    long N = in_sizes[0];
    long E = in_sizes[1];
    const int* esrc = edge_index;
    const int* edst = edge_index + E;

    // d_out is poisoned once and never re-poisoned between replays; we
    // accumulate with atomics, so zero it at the start of every launch.
    zero_kernel<<<(out_size + 255) / 256, 256, 0, stream>>>(out, out_size);

    int  nwords = (int)((N + 15) / 16);
    long nchunk = E / ((long)NBLK * CHUNK);            // 8 for E = 2^24
    bool fast_ok = (ws_size >= (size_t)nwords * 4) &&
                   (N <= (long)NPART * PART_NODES) && (nchunk > 0);

    if (fast_ok) {
        unsigned int* pnt = (unsigned int*)d_ws;
        pack_nt_kernel<<<(nwords + 255) / 256, 256, 0, stream>>>(node_type, pnt, nwords, (int)N);

        edge_score_k<<<NBLK, THREADS, 0, stream>>>(
            pnt, edge_type, esrc, edst, edge_batch, w, out, (int)nchunk);

        long covered = (long)NBLK * nchunk * CHUNK;
        long rem     = E - covered;                    // 0 for this dataset
        if (rem > 0) {
            int tb = (int)((rem + 255) / 256);
            edge_score_simple<<<tb, 256, 0, stream>>>(
                node_type, edge_type, esrc, edst, edge_batch, w, out, covered, E);
        }
    } else {
        int tb = (int)((E + 255) / 256);
        edge_score_simple<<<tb, 256, 0, stream>>>(
            node_type, edge_type, esrc, edst, edge_batch, w, out, 0, E);
    }
}

// Round 16
// 158.725 us; speedup vs baseline: 1.2993x; 1.1483x over previous
//
#include <hip/hip_runtime.h>

typedef int v4i __attribute__((ext_vector_type(4)));
typedef unsigned int u32;
typedef unsigned short u16;
typedef __attribute__((address_space(1))) const u32 gas_u32;
typedef __attribute__((address_space(3))) u32 las_u32;

#define THREADS 1024
#define NWAVES 16
#define EPT 8                            // edges per thread per chunk/iter
#define CHUNK (THREADS * EPT)            // 8192
#define NBLK 256                         // 1 persistent block per CU
#define PART_BITS 19
#define PART_NODES (1 << PART_BITS)      // 524288 nodes per half
#define PART_WORDS (PART_NODES / 16)     // 32768 words = 128 KB
#define TBL 450                          // NUM_RELS * 9
#define FILL_WAVE_WORDS (PART_WORDS / NWAVES)  // 2048 words per wave
#define FILL_PER_WAVE (FILL_WAVE_WORDS / 256)  // 8 DMA instrs per wave
#define ITER_EDGES ((long)NBLK * THREADS * EPT)  // 2,097,152

// ---- barrier/wait helpers (used only by the R8 fallback kernel) ----
#define BAR() do {                                            \
    asm volatile("s_waitcnt lgkmcnt(0)" ::: "memory");        \
    __builtin_amdgcn_s_barrier();                             \
    __builtin_amdgcn_sched_barrier(0);                        \
} while (0)
#define WAITVM(n) do {                                        \
    asm volatile("s_waitcnt vmcnt(" #n ")" ::: "memory");     \
    __builtin_amdgcn_sched_barrier(0);                        \
} while (0)

__global__ void zero_kernel(float* __restrict__ out, int n) {
    int i = blockIdx.x * blockDim.x + threadIdx.x;
    if (i < n) out[i] = 0.0f;
}

// Pack node_type (0..2) into 2 bits/node: 16 nodes per uint32 (256 KB total).
__global__ void pack_nt_kernel(const int* __restrict__ nt,
                               unsigned int* __restrict__ packed,
                               int nwords, int N) {
    int i = blockIdx.x * blockDim.x + threadIdx.x;
    if (i >= nwords) return;
    unsigned int word = 0;
    int base = i * 16;
    if (base + 16 <= N) {
        #pragma unroll
        for (int j = 0; j < 4; ++j) {
            int4 v = *reinterpret_cast<const int4*>(nt + base + j * 4);
            word |= (unsigned)(v.x & 3) << (2 * (j * 4 + 0));
            word |= (unsigned)(v.y & 3) << (2 * (j * 4 + 1));
            word |= (unsigned)(v.z & 3) << (2 * (j * 4 + 2));
            word |= (unsigned)(v.w & 3) << (2 * (j * 4 + 3));
        }
    } else {
        for (int j = 0; base + j < N; ++j)
            word |= (unsigned)(nt[base + j] & 3) << (2 * j);
    }
    packed[i] = word;
}

// DMA one 128 KB half (p=0: low, p=1: high) into LDS. Wave-uniform LDS base
// + lane x 16B (m104 pattern); per-lane global source. Zero VGPR cost.
__device__ __forceinline__ void dma_fill(const u32* __restrict__ pnt,
                                         u32* lds0, int p, int wv, int lane) {
    const u32* g = pnt + (size_t)p * PART_WORDS + wv * FILL_WAVE_WORDS + lane * 4;
    u32* l = lds0 + wv * FILL_WAVE_WORDS;
    #pragma unroll
    for (int i = 0; i < FILL_PER_WAVE; ++i)
        __builtin_amdgcn_global_load_lds((gas_u32*)(g + i * 256),
                                         (las_u32*)(l + i * 256), 16, 0, 0);
}

// ================= TWO-PASS BARRIER-FREE PATH =================
// Pass A: lower node half LDS-resident (immutable). Stream et/es/ed; write
// partial enc (u16) = et*9 + [s<2^19]nts*3 + [d<2^19]ntd. No barriers after
// the prologue -> full TLP latency hiding across 16 waves.
__launch_bounds__(THREADS)
__global__ void pass_a_kernel(const u32* __restrict__ pnt,
                              const int* __restrict__ et_g,
                              const int* __restrict__ es_g,
                              const int* __restrict__ ed_g,
                              u16* __restrict__ enc16,
                              int niter) {
    __shared__ __align__(16) u32 tbl[PART_WORDS];   // 128 KB, read-only after fill
    const int tid  = threadIdx.x;
    const int lane = tid & 63;
    const int wv   = tid >> 6;
    dma_fill(pnt, tbl, 0, wv, lane);
    __syncthreads();                    // one-time drain+barrier

    const long tbase = ((long)blockIdx.x * THREADS + tid) * EPT;
    for (int it = 0; it < niter; ++it) {
        const long e0 = tbase + (long)it * ITER_EDGES;   // 8 consecutive edges
        v4i et0 = __builtin_nontemporal_load((const v4i*)(et_g + e0));
        v4i et1 = __builtin_nontemporal_load((const v4i*)(et_g + e0 + 4));
        v4i sv0 = __builtin_nontemporal_load((const v4i*)(es_g + e0));
        v4i sv1 = __builtin_nontemporal_load((const v4i*)(es_g + e0 + 4));
        v4i dv0 = __builtin_nontemporal_load((const v4i*)(ed_g + e0));
        v4i dv1 = __builtin_nontemporal_load((const v4i*)(ed_g + e0 + 4));
        u32 w[4];
        #pragma unroll
        for (int j = 0; j < 4; ++j) {
            u32 pairv = 0;
            #pragma unroll
            for (int h = 0; h < 2; ++h) {
                const int k = j * 2 + h;
                u32 et = (u32)((k < 4) ? et0[k] : et1[k - 4]);
                u32 s  = (u32)((k < 4) ? sv0[k] : sv1[k - 4]);
                u32 d  = (u32)((k < 4) ? dv0[k] : dv1[k - 4]);
                u32 ws = tbl[(s >> 4) & (PART_WORDS - 1u)];   // junk if s in high half
                u32 wd = tbl[(d >> 4) & (PART_WORDS - 1u)];
                u32 ts = (ws >> ((s & 15u) << 1)) & 3u;
                u32 td = (wd >> ((d & 15u) << 1)) & 3u;
                ts = (s >> PART_BITS) ? 0u : ts;              // mask non-resident
                td = (d >> PART_BITS) ? 0u : td;
                pairv |= (et * 9u + ts * 3u + td) << (h * 16);
            }
            w[j] = pairv;
        }
        v4i wvec; wvec[0] = (int)w[0]; wvec[1] = (int)w[1];
        wvec[2] = (int)w[2]; wvec[3] = (int)w[3];
        *reinterpret_cast<v4i*>(enc16 + e0) = wvec;   // 16B coalesced; keep cached for pass B
    }
}

// Pass B: upper node half LDS-resident. Stream es/ed/enc16/eb; finish enc,
// lw lookup, segmented reduce, 1 atomic/wave fast path. Barrier-free.
__launch_bounds__(THREADS)
__global__ void pass_b_kernel(const u32* __restrict__ pnt,
                              const int* __restrict__ es_g,
                              const int* __restrict__ ed_g,
                              const u16* __restrict__ enc16,
                              const int* __restrict__ eb_g,
                              const float* __restrict__ wt,
                              float* __restrict__ out,
                              int niter) {
    __shared__ __align__(16) u32 tbl[PART_WORDS + TBL];
    float* lw = reinterpret_cast<float*>(tbl + PART_WORDS);
    const int tid  = threadIdx.x;
    const int lane = tid & 63;
    const int wv   = tid >> 6;
    dma_fill(pnt, tbl, 1, wv, lane);    // high half -> tbl[0..32768)
    for (int i = tid; i < TBL; i += THREADS) lw[i] = wt[i];
    __syncthreads();

    const long tbase = ((long)blockIdx.x * THREADS + tid) * EPT;
    for (int it = 0; it < niter; ++it) {
        const long e0 = tbase + (long)it * ITER_EDGES;
        v4i sv0 = __builtin_nontemporal_load((const v4i*)(es_g + e0));
        v4i sv1 = __builtin_nontemporal_load((const v4i*)(es_g + e0 + 4));
        v4i dv0 = __builtin_nontemporal_load((const v4i*)(ed_g + e0));
        v4i dv1 = __builtin_nontemporal_load((const v4i*)(ed_g + e0 + 4));
        v4i ev  = *reinterpret_cast<const v4i*>(enc16 + e0);   // 8 u16 partials
        v4i eb0 = __builtin_nontemporal_load((const v4i*)(eb_g + e0));
        v4i eb1 = __builtin_nontemporal_load((const v4i*)(eb_g + e0 + 4));

        float val[EPT];
        #pragma unroll
        for (int k = 0; k < EPT; ++k) {
            u32 s = (u32)((k < 4) ? sv0[k] : sv1[k - 4]);
            u32 d = (u32)((k < 4) ? dv0[k] : dv1[k - 4]);
            u32 ws = tbl[(s >> 4) & (PART_WORDS - 1u)];
            u32 wd = tbl[(d >> 4) & (PART_WORDS - 1u)];
            u32 ts = (ws >> ((s & 15u) << 1)) & 3u;
            u32 td = (wd >> ((d & 15u) << 1)) & 3u;
            ts = (s >> PART_BITS) ? ts : 0u;   // only high-half contributes here
            td = (d >> PART_BITS) ? td : 0u;
            u32 ep = ((u32)ev[k / 2] >> ((k & 1) * 16)) & 0xFFFFu;
            val[k] = lw[ep + ts * 3u + td];
        }

        int wb0 = __shfl(eb0[0], 0);       // first edge of wave's 512-edge window
        int wbL = __shfl(eb1[3], 63);      // last edge
        if (wb0 == wbL) {                  // sorted => whole window one graph
            float ssum = ((val[0] + val[1]) + (val[2] + val[3]))
                       + ((val[4] + val[5]) + (val[6] + val[7]));
            #pragma unroll
            for (int off = 32; off >= 1; off >>= 1)
                ssum += __shfl_down(ssum, off);
            if (lane == 0) atomicAdd(&out[wb0], ssum);
        } else {
            float acc = 0.0f; int cur = -1;
            #pragma unroll
            for (int k = 0; k < EPT; ++k) {
                int bb = (k < 4) ? eb0[k] : eb1[k - 4];
                if (bb != cur) {
                    if (cur >= 0) atomicAdd(&out[cur], acc);
                    cur = bb; acc = 0.0f;
                }
                acc += val[k];
            }
            if (cur >= 0) atomicAdd(&out[cur], acc);
        }
    }
}

// ================= R8 FALLBACK (proven 114 us) =================
__launch_bounds__(THREADS)
__global__ void edge_score_r8(const u32* __restrict__ pnt,
                              const int* __restrict__ et_g,
                              const int* __restrict__ es_g,
                              const int* __restrict__ ed_g,
                              const int* __restrict__ eb_g,
                              const float* __restrict__ wt,
                              float* __restrict__ out,
                              int nchunk) {
    __shared__ __align__(16) u32 buf[PART_WORDS];   // 128 KB
    __shared__ float lw[TBL];
    const int tid  = threadIdx.x;
    const int lane = tid & 63;
    const int wv   = tid >> 6;
    if (tid < TBL) lw[tid] = wt[tid];

    const long blk0 = (long)blockIdx.x * ((long)nchunk * CHUNK);
    const long lb   = (long)wv * (64 * EPT) + (long)lane * 4;

    v4i etv[2], svv[2], dvv[2];
    #pragma unroll
    for (int j = 0; j < 2; ++j) {
        etv[j] = __builtin_nontemporal_load((const v4i*)(et_g + blk0 + lb + j * 256));
        svv[j] = __builtin_nontemporal_load((const v4i*)(es_g + blk0 + lb + j * 256));
        dvv[j] = __builtin_nontemporal_load((const v4i*)(ed_g + blk0 + lb + j * 256));
    }

    for (int c = 0; c < nchunk; ++c) {
        const long cb = blk0 + (long)c * CHUNK + lb;
        BAR();
        dma_fill(pnt, buf, 0, wv, lane);
        v4i ebv0 = __builtin_nontemporal_load((const v4i*)(eb_g + cb));
        v4i ebv1 = __builtin_nontemporal_load((const v4i*)(eb_g + cb + 256));
        int sv[EPT], dv[EPT], enc[EPT];
        #pragma unroll
        for (int j = 0; j < 2; ++j)
            #pragma unroll
            for (int q = 0; q < 4; ++q) {
                enc[j * 4 + q] = etv[j][q] * 9;
                sv[j * 4 + q]  = svv[j][q];
                dv[j * 4 + q]  = dvv[j][q];
            }
        WAITVM(2); BAR();
        #pragma unroll
        for (int k = 0; k < EPT; ++k) {
            unsigned s = (unsigned)sv[k], d = (unsigned)dv[k];
            bool as = (s >> PART_BITS) == 0u;
            bool ad = (d >> PART_BITS) == 0u;
            u32 ws = buf[as ? ((s >> 4) & (PART_WORDS - 1u)) : 0u];
            u32 wd = buf[ad ? ((d >> 4) & (PART_WORDS - 1u)) : 0u];
            if (as) enc[k] += (int)((ws >> ((s & 15u) << 1)) & 3u) * 3;
            if (ad) enc[k] += (int)((wd >> ((d & 15u) << 1)) & 3u);
        }
        BAR();
        dma_fill(pnt, buf, 1, wv, lane);
        {
            long nb = (c + 1 < nchunk) ? (cb + CHUNK) : cb;
            #pragma unroll
            for (int j = 0; j < 2; ++j) {
                etv[j] = __builtin_nontemporal_load((const v4i*)(et_g + nb + j * 256));
                svv[j] = __builtin_nontemporal_load((const v4i*)(es_g + nb + j * 256));
                dvv[j] = __builtin_nontemporal_load((const v4i*)(ed_g + nb + j * 256));
            }
        }
        WAITVM(6); BAR();
        #pragma unroll
        for (int k = 0; k < EPT; ++k) {
            unsigned s = (unsigned)sv[k], d = (unsigned)dv[k];
            bool as = (s >> PART_BITS) == 1u;
            bool ad = (d >> PART_BITS) == 1u;
            u32 ws = buf[as ? ((s >> 4) & (PART_WORDS - 1u)) : 0u];
            u32 wd = buf[ad ? ((d >> 4) & (PART_WORDS - 1u)) : 0u];
            if (as) enc[k] += (int)((ws >> ((s & 15u) << 1)) & 3u) * 3;
            if (ad) enc[k] += (int)((wd >> ((d & 15u) << 1)) & 3u);
        }
        float val[EPT];
        #pragma unroll
        for (int k = 0; k < EPT; ++k) val[k] = lw[enc[k]];
        int wb0 = __shfl(ebv0[0], 0);
        int wbL = __shfl(ebv1[3], 63);
        if (wb0 == wbL) {
            float ssum = 0.0f;
            #pragma unroll
            for (int k = 0; k < EPT; ++k) ssum += val[k];
            #pragma unroll
            for (int off = 32; off >= 1; off >>= 1)
                ssum += __shfl_down(ssum, off);
            if (lane == 0) atomicAdd(&out[wb0], ssum);
        } else {
            float acc = 0.0f; int cur = -1;
            #pragma unroll
            for (int k = 0; k < EPT; ++k) {
                int bb = (k < 4) ? ebv0[k] : ebv1[k - 4];
                if (bb != cur) {
                    if (cur >= 0) atomicAdd(&out[cur], acc);
                    cur = bb; acc = 0.0f;
                }
                acc += val[k];
            }
            if (cur >= 0) atomicAdd(&out[cur], acc);
        }
    }
}

// Per-edge fallback / tail kernel (direct gathers; correctness path).
__global__ void edge_score_simple(const int* __restrict__ nt,
                                  const int* __restrict__ et,
                                  const int* __restrict__ es,
                                  const int* __restrict__ ed,
                                  const int* __restrict__ eb,
                                  const float* __restrict__ w,
                                  float* __restrict__ out,
                                  long e0, long E) {
    long e = e0 + (long)blockIdx.x * blockDim.x + threadIdx.x;
    if (e >= E) return;
    int enc = et[e] * 9 + nt[es[e]] * 3 + nt[ed[e]];
    atomicAdd(&out[eb[e]], w[enc]);
}

extern "C" void kernel_launch(void* const* d_in, const int* in_sizes, int n_in,
                              void* d_out, int out_size, void* d_ws, size_t ws_size,
                              hipStream_t stream) {
    const int*   node_type  = (const int*)d_in[0];
    const int*   edge_type  = (const int*)d_in[1];
    const int*   edge_index = (const int*)d_in[2];   // [2, E]: src then dst
    const int*   edge_batch = (const int*)d_in[3];
    const float* w          = (const float*)d_in[4];
    float* out = (float*)d_out;

    long N = in_sizes[0];
    long E = in_sizes[1];
    const int* esrc = edge_index;
    const int* edst = edge_index + E;

    // d_out is poisoned once and never re-poisoned between replays; we
    // accumulate with atomics, so zero it at the start of every launch.
    zero_kernel<<<(out_size + 255) / 256, 256, 0, stream>>>(out, out_size);

    int    nwords   = (int)((N + 15) / 16);
    size_t need_pnt = (size_t)2 * PART_WORDS * 4;            // 256 KB (full table)
    size_t need_two = need_pnt + (size_t)E * 2;              // + enc16 (u16/edge)
    long   niter    = E / ITER_EDGES;                        // 8 for E = 2^24
    long   nchunk   = E / ((long)NBLK * CHUNK);              // 8 for E = 2^24
    bool   n_ok     = (N <= 2L * PART_NODES);

    if (n_ok && niter > 0 && ws_size >= need_two) {
        // -------- two-pass barrier-free path --------
        u32* pnt   = (u32*)d_ws;
        u16* enc16 = (u16*)((char*)d_ws + need_pnt);
        pack_nt_kernel<<<(nwords + 255) / 256, 256, 0, stream>>>(node_type, pnt, nwords, (int)N);

        pass_a_kernel<<<NBLK, THREADS, 0, stream>>>(
            pnt, edge_type, esrc, edst, enc16, (int)niter);
        pass_b_kernel<<<NBLK, THREADS, 0, stream>>>(
            pnt, esrc, edst, enc16, edge_batch, w, out, (int)niter);

        long covered = niter * ITER_EDGES;
        long rem     = E - covered;                          // 0 for this dataset
        if (rem > 0) {
            int tb = (int)((rem + 255) / 256);
            edge_score_simple<<<tb, 256, 0, stream>>>(
                node_type, edge_type, esrc, edst, edge_batch, w, out, covered, E);
        }
    } else if (n_ok && nchunk > 0 && ws_size >= need_pnt) {
        // -------- R8 fallback (proven clean) --------
        u32* pnt = (u32*)d_ws;
        pack_nt_kernel<<<(nwords + 255) / 256, 256, 0, stream>>>(node_type, pnt, nwords, (int)N);
        edge_score_r8<<<NBLK, THREADS, 0, stream>>>(
            pnt, edge_type, esrc, edst, edge_batch, w, out, (int)nchunk);
        long covered = (long)NBLK * nchunk * CHUNK;
        long rem     = E - covered;
        if (rem > 0) {
            int tb = (int)((rem + 255) / 256);
            edge_score_simple<<<tb, 256, 0, stream>>>(
                node_type, edge_type, esrc, edst, edge_batch, w, out, covered, E);
        }
    } else {
        int tb = (int)((E + 255) / 256);
        edge_score_simple<<<tb, 256, 0, stream>>>(
            node_type, edge_type, esrc, edst, edge_batch, w, out, 0, E);
    }
}